// Round 5
// baseline (273.757 us; speedup 1.0000x reference)
//
#include <hip/hip_runtime.h>

#define NB 4
#define NC 512
#define NT 4096
#define NTILE 528   // 32*33/2 triangular 128x128 tiles per batch

typedef __attribute__((ext_vector_type(4))) float f32x4;
typedef __attribute__((ext_vector_type(8))) short short8;

typedef const __attribute__((address_space(1))) unsigned int* gp1_t;
typedef __attribute__((address_space(3))) unsigned int* lp3_t;

__device__ __forceinline__ void gload16(const short* g, short* l) {
  // async global->LDS, 16B/lane; LDS dest = wave-uniform base + lane*16
  __builtin_amdgcn_global_load_lds((gp1_t)g, (lp3_t)l, 16, 0, 0);
}

// Raw barrier / waitcnt with memory clobbers. Counted vmcnt keeps prefetch
// loads in flight across barriers.
// ROUND-3 LESSON: prefetch depth-1 is catastrophic; keep depth >= 2.
// ROUND-4 THEORY: 3-block/CU 128x128 GEMMs are LDS-BW-bound (48 KB/kstep x3
// blocks ~= 93% of the LDS pipe). Fix = fewer LDS bytes per FLOP, not
// scheduling.
#define BARRIER()  asm volatile("s_barrier" ::: "memory")
#define WAITVM0()  asm volatile("s_waitcnt vmcnt(0)" ::: "memory")
#define WAITVM4()  asm volatile("s_waitcnt vmcnt(4)" ::: "memory")
#define WAITVM6()  asm volatile("s_waitcnt vmcnt(6)" ::: "memory")
#define WAITVM8()  asm volatile("s_waitcnt vmcnt(8)" ::: "memory")
#define WAITVM12() asm volatile("s_waitcnt vmcnt(12)" ::: "memory")
#define WAITVM16() asm volatile("s_waitcnt vmcnt(16)" ::: "memory")

__device__ __forceinline__ short f2bf(float f) {
  union { float f; unsigned u; } v; v.f = f;
  unsigned r = v.u + 0x7fffu + ((v.u >> 16) & 1u);
  return (short)(r >> 16);
}
__device__ __forceinline__ float bf2f(short s) {
  union { unsigned u; float f; } v; v.u = ((unsigned)(unsigned short)s) << 16;
  return v.f;
}

// ---------------------------------------------------------------------------
// LDS XOR swizzle (T2): staged buffers are rows x 32 shorts (64 B rows).
// Store column-group cg at cg ^ ((row>>1)&3); applied via per-lane GLOBAL
// source column (rule 21) + read column. Verified round 2: bank conflicts
// 4.33M -> 0.
// ---------------------------------------------------------------------------
#define SCOL_SWZ(lane) ((((lane) & 3) ^ (((lane) >> 3) & 3)) * 8)
#define FKO_SWZ(lane)  (((((lane) >> 4) ^ (((lane) >> 1) & 3)) & 3) * 8)

// ---------------------------------------------------------------------------
// 128x128 NT-GEMM core (4x4 acc), prefetch depth NBUF-1. Kept for the
// grid-512 kernels (k_out via template, k_pv inline).
// ---------------------------------------------------------------------------
template <int NBUF>
__device__ __forceinline__ void gemm_tile(const short* __restrict__ A, int lda,
                                          const short* __restrict__ Bg, int ldb,
                                          int m0, int n0, int ksteps,
                                          f32x4 (&acc)[4][4], short* lds) {
  const int tid  = threadIdx.x;
  const int lane = tid & 63;
  const int wv   = tid >> 6;
  const int wm = (wv >> 1) * 64;
  const int wn = (wv & 1) * 64;
  const int srow = wv * 16 + (lane >> 2);
  const int scol = SCOL_SWZ(lane);
  const int fm  = lane & 15;
  const int fko = FKO_SWZ(lane);

  const short* Ap0 = A  + (size_t)(m0 + srow) * lda + scol;
  const short* Ap1 = Ap0 + (size_t)64 * lda;
  const short* Bp0 = Bg + (size_t)(n0 + srow) * ldb + scol;
  const short* Bp1 = Bp0 + (size_t)64 * ldb;

  auto issue = [&](int kt) {
    short* base = lds + (kt % NBUF) * 8192;
    const int k0 = kt * 32;
    gload16(Ap0 + k0, base + wv * 512);
    gload16(Ap1 + k0, base + 2048 + wv * 512);
    gload16(Bp0 + k0, base + 4096 + wv * 512);
    gload16(Bp1 + k0, base + 6144 + wv * 512);
  };

  issue(0);
#pragma unroll
  for (int p = 1; p < NBUF - 1; ++p)
    if (p < ksteps) issue(p);

  for (int kt = 0; kt < ksteps; ++kt) {
    const short* As = lds + (kt % NBUF) * 8192;
    const short* Bs = As + 4096;
    if (kt) BARRIER();
    if constexpr (NBUF == 5) {
      if (kt + 4 < ksteps)      { issue(kt + 4); WAITVM16(); }
      else if (kt + 3 < ksteps) { WAITVM12(); }
      else if (kt + 2 < ksteps) { WAITVM8(); }
      else if (kt + 1 < ksteps) { WAITVM4(); }
      else                      { WAITVM0(); }
    } else {  // NBUF == 3, depth-2
      if (kt + 2 < ksteps)      { issue(kt + 2); WAITVM8(); }
      else if (kt + 1 < ksteps) { WAITVM4(); }
      else                      { WAITVM0(); }
    }
    BARRIER();
    short8 af[4], bfr[4];
#pragma unroll
    for (int i = 0; i < 4; ++i)
      af[i] = *(const short8*)(As + (wm + i * 16 + fm) * 32 + fko);
#pragma unroll
    for (int j = 0; j < 4; ++j)
      bfr[j] = *(const short8*)(Bs + (wn + j * 16 + fm) * 32 + fko);
#pragma unroll
    for (int i = 0; i < 4; ++i)
#pragma unroll
      for (int j = 0; j < 4; ++j)
        acc[i][j] = __builtin_amdgcn_mfma_f32_16x16x32_bf16(af[i], bfr[j], acc[i][j], 0, 0, 0);
  }
}

// ---------------------------------------------------------------------------
// 128x256 NT-GEMM core (4x8 acc, 128 VGPR), NBUF=3, depth-2.
// Per kstep: write 24 KB + read 48 KB = 72 KB LDS for 128 MFMAs
// (0.56 KB/MFMA vs 0.75 for the 128x128 core -- 25% LDS-traffic cut).
// 6 DMAs per kstep -> vmcnt multiples of 6. LDS = 3 x 12288 shorts = 72 KB,
// 2 blocks/CU.
// Waves 2x2: wave tile 64x128 (wm = (wv>>1)*64, wn = (wv&1)*128).
// ---------------------------------------------------------------------------
__device__ __forceinline__ void gemm_tile256(const short* __restrict__ A, int lda,
                                             const short* __restrict__ Bg, int ldb,
                                             int m0, int n0, int ksteps,
                                             f32x4 (&acc)[4][8], short* lds) {
  const int tid  = threadIdx.x;
  const int lane = tid & 63;
  const int wv   = tid >> 6;
  const int wm = (wv >> 1) * 64;
  const int wn = (wv & 1) * 128;
  const int srow = wv * 16 + (lane >> 2);
  const int scol = SCOL_SWZ(lane);
  const int fm  = lane & 15;
  const int fko = FKO_SWZ(lane);

  const short* Ap0 = A  + (size_t)(m0 + srow) * lda + scol;
  const short* Ap1 = Ap0 + (size_t)64 * lda;
  const short* Bp0 = Bg + (size_t)(n0 + srow) * ldb + scol;
  const short* Bp1 = Bp0 + (size_t)64 * ldb;
  const short* Bp2 = Bp0 + (size_t)128 * ldb;
  const short* Bp3 = Bp0 + (size_t)192 * ldb;

  auto issue = [&](int kt) {
    short* base = lds + (kt % 3) * 12288;
    const int k0 = kt * 32;
    gload16(Ap0 + k0, base + wv * 512);
    gload16(Ap1 + k0, base + 2048 + wv * 512);
    gload16(Bp0 + k0, base + 4096 + wv * 512);
    gload16(Bp1 + k0, base + 6144 + wv * 512);
    gload16(Bp2 + k0, base + 8192 + wv * 512);
    gload16(Bp3 + k0, base + 10240 + wv * 512);
  };

  issue(0);
  if (ksteps > 1) issue(1);
  for (int kt = 0; kt < ksteps; ++kt) {
    const short* As = lds + (kt % 3) * 12288;
    const short* Bs = As + 4096;                 // B rows 0..255 at Bs + r*32
    if (kt) BARRIER();
    if (kt + 2 < ksteps)      { issue(kt + 2); WAITVM12(); }
    else if (kt + 1 < ksteps) { WAITVM6(); }
    else                      { WAITVM0(); }
    BARRIER();
    short8 af[4], bfr[8];
#pragma unroll
    for (int i = 0; i < 4; ++i)
      af[i] = *(const short8*)(As + (wm + i * 16 + fm) * 32 + fko);
#pragma unroll
    for (int j = 0; j < 8; ++j)
      bfr[j] = *(const short8*)(Bs + (wn + j * 16 + fm) * 32 + fko);
#pragma unroll
    for (int i = 0; i < 4; ++i)
#pragma unroll
      for (int j = 0; j < 8; ++j)
        acc[i][j] = __builtin_amdgcn_mfma_f32_16x16x32_bf16(af[i], bfr[j], acc[i][j], 0, 0, 0);
  }
}

#define ACC_INIT                                  \
  f32x4 acc[4][4];                                \
  {                                               \
    const f32x4 z = {0.f, 0.f, 0.f, 0.f};         \
    for (int i = 0; i < 4; ++i)                   \
      for (int j = 0; j < 4; ++j) acc[i][j] = z;  \
  }

#define ACC_INIT256                               \
  f32x4 acc[4][8];                                \
  {                                               \
    const f32x4 z = {0.f, 0.f, 0.f, 0.f};         \
    for (int i = 0; i < 4; ++i)                   \
      for (int j = 0; j < 8; ++j) acc[i][j] = z;  \
  }

#define EPI_IDX                                   \
  const int lane = threadIdx.x & 63;              \
  const int wave = threadIdx.x >> 6;              \
  const int wm = (wave >> 1) * 64;                \
  const int wn = (wave & 1) * 64;

#define EPI_IDX256                                \
  const int lane = threadIdx.x & 63;              \
  const int wave = threadIdx.x >> 6;              \
  const int wm = (wave >> 1) * 64;                \
  const int wn = (wave & 1) * 128;

#define GEMM_LDS256 __shared__ short lds[36864];  // 3 bufs x 24 KB = 72 KB
#define GEMM_LDS5   __shared__ short lds[40960];  // 5 bufs x 16 KB = 80 KB

// ---------------------------------------------------------------------------
// XCD-locality swizzle for flat grids of (row-stripe, 4 col-chunks) (k_out).
// ---------------------------------------------------------------------------
__device__ __forceinline__ void xcd_rowchunk(int x, int nrows, int& row, int& chunk) {
  const int xcd  = x & 7;
  const int slot = x >> 3;
  row   = nrows - 1 - (xcd + 8 * (slot >> 2));
  chunk = slot & 3;
}

// ---------------------------------------------------------------------------
// Work-balanced row map for k_pv (round-2 verified: every CU = 132 ksteps).
// ---------------------------------------------------------------------------
__device__ __forceinline__ void pv_rowchunk(int x, int z, int& bm, int& chunk) {
  const int xcd  = x & 7;
  const int slot = x >> 3;           // 0..15
  int ridx = slot >> 2;              // 0..3
  if (z >= 2) ridx = 3 - ridx;
  bm = (ridx == 0) ? (31 - xcd)
     : (ridx == 1) ? (23 - xcd)
     : (ridx == 2) ? (8 + xcd)
                   : xcd;
  chunk = slot & 3;
}

// ---------------------------------------------------------------------------
// x [B,C,T] f32 -> xT [B,T,C] bf16 (tiled transpose through LDS)
// ---------------------------------------------------------------------------
__global__ __launch_bounds__(256) void k_transpose(const float* __restrict__ x,
                                                   short* __restrict__ xT) {
  __shared__ float tile[32][33];
  const int b  = blockIdx.z;
  const int t0 = blockIdx.x * 32;
  const int c0 = blockIdx.y * 32;
  const int tx = threadIdx.x & 31;
  const int ty = threadIdx.x >> 5;
  const float* xp = x + ((size_t)b * NC + c0) * NT + t0;
#pragma unroll
  for (int i = 0; i < 32; i += 8)
    tile[ty + i][tx] = xp[(size_t)(ty + i) * NT + tx];
  __syncthreads();
  short* op = xT + ((size_t)b * NT + t0) * NC + c0;
#pragma unroll
  for (int i = 0; i < 32; i += 8)
    op[(size_t)(ty + i) * NC + tx] = f2bf(tile[tx][ty + i]);
}

// f32 -> bf16 conversion of all 4 weight matrices in one launch
__global__ __launch_bounds__(256) void k_wcvt(const float* __restrict__ s0, const float* __restrict__ s1,
                                              const float* __restrict__ s2, const float* __restrict__ s3,
                                              short* __restrict__ d0, short* __restrict__ d1,
                                              short* __restrict__ d2, short* __restrict__ d3) {
  const float* s; short* d;
  switch (blockIdx.y) {
    case 0: s = s0; d = d0; break;
    case 1: s = s1; d = d1; break;
    case 2: s = s2; d = d2; break;
    default: s = s3; d = d3; break;
  }
  const int i = (blockIdx.x * 256 + threadIdx.x) * 4;
  const float4 v = *(const float4*)(s + i);
  short4 o;
  o.x = f2bf(v.x); o.y = f2bf(v.y); o.z = f2bf(v.z); o.w = f2bf(v.w);
  *(short4*)(d + i) = o;
}

// ---------------------------------------------------------------------------
// Fused Q/K/V projections, 128x256 tiles. blockIdx.y selects Q/K/VT.
// grid.x = 64. XCD-contiguous logical order via sw = (x&7)*8 + (x>>3).
//   y<2 : row = sw>>1 (32 rows of 128 t), chunk = sw&1 (2 chunks of 256 ch)
//   y=2 : m0 = (sw&3)*128 (Wv rows), n0 = (sw>>2)*256 (t-cols)
// ---------------------------------------------------------------------------
__global__ __launch_bounds__(256, 2) void k_qkv(const short* __restrict__ xT,
                                                const short* __restrict__ Wq,
                                                const float* __restrict__ bq,
                                                const short* __restrict__ Wk,
                                                const float* __restrict__ bk,
                                                const short* __restrict__ Wv,
                                                const float* __restrict__ bv,
                                                short* __restrict__ Q,
                                                short* __restrict__ K,
                                                short* __restrict__ VT) {
  GEMM_LDS256;
  const int b = blockIdx.z;
  const int y = blockIdx.y;
  const int x = blockIdx.x;
  const int sw = (x & 7) * 8 + (x >> 3);
  const short* Xb = xT + (size_t)b * NT * NC;
  ACC_INIT256;
  if (y < 2) {
    const short* W = (y == 0) ? Wq : Wk;
    const float* bias = (y == 0) ? bq : bk;
    short* O = ((y == 0) ? Q : K) + (size_t)b * NT * NC;
    const int m0 = (sw >> 1) * 128;
    const int n0 = (sw & 1) * 256;
    gemm_tile256(Xb, NC, W, NC, m0, n0, NC / 32, acc, lds);
    EPI_IDX256;
#pragma unroll
    for (int j = 0; j < 8; ++j) {
      const int n = n0 + wn + j * 16 + (lane & 15);
      const float bv_ = bias[n];
#pragma unroll
      for (int i = 0; i < 4; ++i) {
        const int mb = m0 + wm + i * 16 + ((lane >> 4) * 4);
#pragma unroll
        for (int r = 0; r < 4; ++r)
          O[(size_t)(mb + r) * NC + n] = f2bf(acc[i][j][r] + bv_);
      }
    }
  } else {
    const int m0 = (sw & 3) * 128;   // Wv row chunk
    const int n0 = (sw >> 2) * 256;  // xT row-stripe (B operand)
    gemm_tile256(Wv, NC, Xb, NC, m0, n0, NC / 32, acc, lds);
    EPI_IDX256;
    short* O = VT + (size_t)b * NC * NT;
#pragma unroll
    for (int j = 0; j < 8; ++j) {
      const int n = n0 + wn + j * 16 + (lane & 15);
#pragma unroll
      for (int i = 0; i < 4; ++i) {
        const int mb = m0 + wm + i * 16 + ((lane >> 4) * 4);
#pragma unroll
        for (int r = 0; r < 4; ++r)
          O[(size_t)(mb + r) * NT + n] = f2bf(acc[i][j][r] + bv[mb + r]);
      }
    }
  }
}

// ---------------------------------------------------------------------------
// Scores + softmax numerator, 128x256 QK tiles (bn-PAIRS), packed-P layout
// UNCHANGED (each wave owns one 128-half: waves 0,2 -> bn=2pk, waves 1,3 ->
// bn=2pk+1, so each half writes its own 128x128 tile slot; k_pv untouched).
// Enumeration: (bm, pk) with pk <= bm/2; 272 blocks/batch. Flat p decode via
// base(2a)=a(a+1), base(2a+1)=(a+1)^2. XCD map: p = (x&7)*34 + (x>>3).
// Halves with bn > bm (bm even, pk=bm/2) skip the epilogue (3% MFMA waste).
// ---------------------------------------------------------------------------
__global__ __launch_bounds__(256, 2) void k_scores(const short* __restrict__ Q,
                                                   const short* __restrict__ K,
                                                   short* __restrict__ P,
                                                   float* __restrict__ Lrow) {
  const int x = blockIdx.x;
  const int p = (x & 7) * 34 + (x >> 3);   // XCD-contiguous, bijective (272=8*34)
  int bm = 0, pk = 0;
#pragma unroll
  for (int a = 0; a < 16; ++a) {
    const int e0 = a * (a + 1);
    const int e1 = (a + 1) * (a + 1);
    const int e2 = (a + 1) * (a + 2);
    if (p < e1) { bm = 2 * a; pk = p - e0; break; }
    if (p < e2) { bm = 2 * a + 1; pk = p - e1; break; }
  }
  GEMM_LDS256;
  const int b  = blockIdx.z;
  const int m0 = bm * 128;
  const int n0 = pk * 256;
  ACC_INIT256;
  gemm_tile256(Q + (size_t)b * NT * NC, NC, K + (size_t)b * NT * NC, NC,
               m0, n0, NC / 32, acc, lds);
  const int lane = threadIdx.x & 63;
  const int wave = threadIdx.x >> 6;
  const int wm = (wave >> 1) * 64;
  const int half = wave & 1;
  const int bn = 2 * pk + half;
  if (bn > bm) return;                      // fully-masked half
  const float kls = 0.06376070265f;         // 512^-0.5 * log2(e)
  short* Tp = P + ((size_t)b * NTILE + (size_t)(bm * (bm + 1) / 2 + bn)) * 16384;
  float* Lp = Lrow + (size_t)b * NT;
  float psum[4][4];
#pragma unroll
  for (int i = 0; i < 4; ++i)
#pragma unroll
    for (int r = 0; r < 4; ++r) psum[i][r] = 0.f;

  if (bn < bm) {
    // interior: causal mask always true -- branchless, packed bf16 convert
#pragma unroll
    for (int j = 0; j < 8; ++j) {
      const int ln = j * 16 + (lane & 15);
#pragma unroll
      for (int i = 0; i < 4; ++i) {
        const int lmb = wm + i * 16 + ((lane >> 4) * 4);
        const float e0 = exp2f(acc[i][j][0] * kls);
        const float e1 = exp2f(acc[i][j][1] * kls);
        const float e2 = exp2f(acc[i][j][2] * kls);
        const float e3 = exp2f(acc[i][j][3] * kls);
        unsigned pk01, pk23;
        asm("v_cvt_pk_bf16_f32 %0, %1, %2" : "=v"(pk01) : "v"(e0), "v"(e1));
        asm("v_cvt_pk_bf16_f32 %0, %1, %2" : "=v"(pk23) : "v"(e2), "v"(e3));
        Tp[(lmb + 0) * 128 + ln] = (short)(pk01 & 0xffffu);
        Tp[(lmb + 1) * 128 + ln] = (short)(pk01 >> 16);
        Tp[(lmb + 2) * 128 + ln] = (short)(pk23 & 0xffffu);
        Tp[(lmb + 3) * 128 + ln] = (short)(pk23 >> 16);
        union { unsigned u; float f; } c0, c1, c2, c3;
        c0.u = pk01 << 16; c1.u = pk01 & 0xffff0000u;
        c2.u = pk23 << 16; c3.u = pk23 & 0xffff0000u;
        psum[i][0] += c0.f; psum[i][1] += c1.f;
        psum[i][2] += c2.f; psum[i][3] += c3.f;
      }
    }
  } else {
    // diagonal tile: evaluate mask per element
#pragma unroll
    for (int j = 0; j < 8; ++j) {
      const int ln = j * 16 + (lane & 15);
      const int n  = bn * 128 + ln;
#pragma unroll
      for (int i = 0; i < 4; ++i) {
        const int lmb = wm + i * 16 + ((lane >> 4) * 4);
#pragma unroll
        for (int r = 0; r < 4; ++r) {
          const int m = m0 + lmb + r;
          float pr = 0.f;
          short pb = 0;
          if (n <= m) {
            pb = f2bf(exp2f(acc[i][j][r] * kls));
            pr = bf2f(pb);
          }
          Tp[(lmb + r) * 128 + ln] = pb;
          psum[i][r] += pr;
        }
      }
    }
  }
#pragma unroll
  for (int i = 0; i < 4; ++i)
#pragma unroll
    for (int r = 0; r < 4; ++r) {
      float v = psum[i][r];
      v += __shfl_xor(v, 1);
      v += __shfl_xor(v, 2);
      v += __shfl_xor(v, 4);
      v += __shfl_xor(v, 8);
      if ((lane & 15) == 0) {
        const int m = m0 + wm + i * 16 + ((lane >> 4) * 4) + r;
        atomicAdd(&Lp[m], v);
      }
    }
}

// ---------------------------------------------------------------------------
// PV: H[t,c] = (1/L[t]) * sum_{s<=t} P[t,s] * VT[c,s]  -> bf16 [T,C]
// flat grid (128, 1, B): XCD-grouped, work-balanced row map (see pv_rowchunk).
// Depth-4 prefetch (5 LDS buffers, 80 KB): 2 blocks/CU either way.
// ---------------------------------------------------------------------------
__global__ __launch_bounds__(256, 2) void k_pv(const short* __restrict__ P,
                                               const short* __restrict__ VT,
                                               const float* __restrict__ Lr,
                                               short* __restrict__ H) {
  GEMM_LDS5;
  const int b = blockIdx.z;
  int bm, chunk;
  pv_rowchunk((int)blockIdx.x, b, bm, chunk);
  const int m0 = bm * 128;
  const int n0 = chunk * 128;
  const int ksteps = (bm + 1) * 4;

  const short* Ptri = P + ((size_t)b * NTILE + (size_t)bm * (bm + 1) / 2) * 16384;
  const short* Bg   = VT + (size_t)b * NC * NT;

  ACC_INIT;
  const int tid  = threadIdx.x;
  const int lane = tid & 63;
  const int wv   = tid >> 6;
  const int wm = (wv >> 1) * 64;
  const int wn = (wv & 1) * 64;
  const int srow = wv * 16 + (lane >> 2);
  const int scol = SCOL_SWZ(lane);
  const int fm  = lane & 15;
  const int fko = FKO_SWZ(lane);

  const short* Bp0 = Bg + (size_t)(n0 + srow) * NT + scol;
  const short* Bp1 = Bp0 + (size_t)64 * NT;

  auto issue = [&](int kt) {
    short* base = lds + (kt % 5) * 8192;
    const short* At = Ptri + (size_t)(kt >> 2) * 16384 + (kt & 3) * 32;
    const short* Ap0 = At + srow * 128 + scol;
    const int k0 = kt * 32;
    gload16(Ap0, base + wv * 512);
    gload16(Ap0 + 64 * 128, base + 2048 + wv * 512);
    gload16(Bp0 + k0, base + 4096 + wv * 512);
    gload16(Bp1 + k0, base + 6144 + wv * 512);
  };

  issue(0);
#pragma unroll
  for (int p = 1; p < 4; ++p)
    if (p < ksteps) issue(p);
  for (int kt = 0; kt < ksteps; ++kt) {
    const short* As = lds + (kt % 5) * 8192;
    const short* Bs = As + 4096;
    if (kt) BARRIER();
    if (kt + 4 < ksteps)      { issue(kt + 4); WAITVM16(); }
    else if (kt + 3 < ksteps) { WAITVM12(); }
    else if (kt + 2 < ksteps) { WAITVM8(); }
    else if (kt + 1 < ksteps) { WAITVM4(); }
    else                      { WAITVM0(); }
    BARRIER();
    short8 af[4], bfr[4];
#pragma unroll
    for (int i = 0; i < 4; ++i)
      af[i] = *(const short8*)(As + (wm + i * 16 + fm) * 32 + fko);
#pragma unroll
    for (int j = 0; j < 4; ++j)
      bfr[j] = *(const short8*)(Bs + (wn + j * 16 + fm) * 32 + fko);
#pragma unroll
    for (int i = 0; i < 4; ++i)
#pragma unroll
      for (int j = 0; j < 4; ++j)
        acc[i][j] = __builtin_amdgcn_mfma_f32_16x16x32_bf16(af[i], bfr[j], acc[i][j], 0, 0, 0);
  }

  const float* L = Lr + (size_t)b * NT;
  short* Hp = H + (size_t)b * NT * NC;
#pragma unroll
  for (int i = 0; i < 4; ++i) {
    const int mb = m0 + wm + i * 16 + ((lane >> 4) * 4);
    float rinv[4];
#pragma unroll
    for (int r = 0; r < 4; ++r) rinv[r] = 1.f / L[mb + r];
#pragma unroll
    for (int j = 0; j < 4; ++j) {
      const int n = n0 + wn + j * 16 + (lane & 15);
#pragma unroll
      for (int r = 0; r < 4; ++r)
        Hp[(size_t)(mb + r) * NC + n] = f2bf(acc[i][j][r] * rinv[r]);
    }
  }
}

// ---------------------------------------------------------------------------
// Output projection + residual: out[o,t] = Wp·H^T + bp[o] + x[o,t], fp32.
// flat grid (128, 1, B): XCD-grouped so one H row-stripe serves 4 m0 chunks.
// ---------------------------------------------------------------------------
__global__ __launch_bounds__(256, 2) void k_out(const short* __restrict__ W,
                                                const short* __restrict__ H,
                                                const float* __restrict__ bias,
                                                const float* __restrict__ x,
                                                float* __restrict__ out) {
  GEMM_LDS5;
  const int b = blockIdx.z;
  int row, chunk;
  xcd_rowchunk((int)blockIdx.x, NT / 128, row, chunk);
  const int n0 = row * 128;    // H row-stripe (B operand)
  const int m0 = chunk * 128;  // Wp row chunk
  ACC_INIT;
  gemm_tile<5>(W, NC, H + (size_t)b * NT * NC, NC, m0, n0, NC / 32, acc, lds);
  EPI_IDX;
#pragma unroll
  for (int j = 0; j < 4; ++j) {
    const int n = n0 + wn + j * 16 + (lane & 15);
#pragma unroll
    for (int i = 0; i < 4; ++i) {
      const int mb = m0 + wm + i * 16 + ((lane >> 4) * 4);
#pragma unroll
      for (int r = 0; r < 4; ++r) {
        const int m = mb + r;
        const size_t idx = ((size_t)b * NC + m) * NT + n;
        out[idx] = acc[i][j][r] + bias[m] + x[idx];
      }
    }
  }
}

// ---------------------------------------------------------------------------
extern "C" void kernel_launch(void* const* d_in, const int* in_sizes, int n_in,
                              void* d_out, int out_size, void* d_ws, size_t ws_size,
                              hipStream_t stream) {
  (void)in_sizes; (void)n_in; (void)out_size; (void)ws_size;
  const float* x  = (const float*)d_in[0];
  const float* Wq = (const float*)d_in[1];
  const float* bq = (const float*)d_in[2];
  const float* Wk = (const float*)d_in[3];
  const float* bk = (const float*)d_in[4];
  const float* Wv = (const float*)d_in[5];
  const float* bv = (const float*)d_in[6];
  const float* Wp = (const float*)d_in[7];
  const float* bp = (const float*)d_in[8];
  float* out = (float*)d_out;

  char* ws = (char*)d_ws;
  size_t off = 0;
  auto alloc = [&](size_t bytes) { char* p = ws + off; off += bytes; return p; };
  short* xT  = (short*)alloc((size_t)NB * NT * NC * 2);
  short* Qb  = (short*)alloc((size_t)NB * NT * NC * 2);
  short* Kb  = (short*)alloc((size_t)NB * NT * NC * 2);
  short* VTb = (short*)alloc((size_t)NB * NC * NT * 2);
  short* Hb  = (short*)alloc((size_t)NB * NT * NC * 2);
  short* Wqb = (short*)alloc((size_t)NC * NC * 2);
  short* Wkb = (short*)alloc((size_t)NC * NC * 2);
  short* Wvb = (short*)alloc((size_t)NC * NC * 2);
  short* Wpb = (short*)alloc((size_t)NC * NC * 2);
  float* Lr  = (float*)alloc((size_t)NB * NT * 4);
  short* Pb  = (short*)alloc((size_t)NB * NTILE * 16384 * 2);  // 69 MB packed

  hipMemsetAsync(Lr, 0, (size_t)NB * NT * 4, stream);

  const dim3 blk(256);
  k_wcvt<<<dim3(NC * NC / 1024, 4), blk, 0, stream>>>(Wq, Wk, Wv, Wp, Wqb, Wkb, Wvb, Wpb);

  k_transpose<<<dim3(NT / 32, NC / 32, NB), blk, 0, stream>>>(x, xT);

  k_qkv<<<dim3(64, 3, NB), blk, 0, stream>>>(xT, Wqb, bq, Wkb, bk, Wvb, bv, Qb, Kb, VTb);

  k_scores<<<dim3(272, 1, NB), blk, 0, stream>>>(Qb, Kb, Pb, Lr);
  k_pv<<<dim3(128, 1, NB), blk, 0, stream>>>(Pb, VTb, Lr, Hb);
  k_out<<<dim3(128, 1, NB), blk, 0, stream>>>(Wpb, Hb, bp, x, out);
}